// Round 2
// baseline (16.124 us; speedup 1.0000x reference)
//
#include <hip/hip_runtime.h>
#include <hip/hip_bf16.h>

// Span-mean aggregation:
//   out[b,s,:] = (s < lengths[b]) ? mean(x[b, i0..j0), :]) : 0
// One block per (b,s), blockDim = D/4 lanes (192 for D=768); each thread
// owns one float4 column, sums the span's rows, scales, stores.
//
// R2 changes vs R1:
//  - lengths + spans loads hoisted & issued concurrently (was: serial
//    lengths -> branch -> spans chain = 2 dependent memory round trips).
//  - n==8 fast path: 8 unconditional loads with static offsets (spans are
//    fixed-width in this problem; generic loop kept as fallback).

__global__ __launch_bounds__(256) void span_mean_kernel(
        const float4* __restrict__ x,
        const int* __restrict__ lengths,
        const int* __restrict__ spans,
        float4* __restrict__ out,
        int S, int T, int D4) {
    const int bs = blockIdx.x;          // b * S + s
    const int b  = bs / S;
    const int s  = bs - b * S;

    // Issue all block-uniform loads up front, no deps between them.
    const int len = lengths[b];
    const int i0  = spans[2 * bs + 0];
    const int j0  = spans[2 * bs + 1];

    const int d = threadIdx.x;
    float4* __restrict__ o = out + (size_t)bs * D4;

    if (s >= len) {
        if (d < D4) o[d] = make_float4(0.f, 0.f, 0.f, 0.f);
        return;
    }

    const int n = j0 - i0;
    const float inv = 1.0f / (float)(n > 1 ? n : 1);
    const float4* __restrict__ p = x + ((size_t)b * T + i0) * (size_t)D4 + d;

    if (d < D4) {
        float4 acc;
        if (n == 8) {
            // Fast path: all 8 loads issue unconditionally, static strides.
            float4 v0 = p[0 * (size_t)D4];
            float4 v1 = p[1 * (size_t)D4];
            float4 v2 = p[2 * (size_t)D4];
            float4 v3 = p[3 * (size_t)D4];
            float4 v4 = p[4 * (size_t)D4];
            float4 v5 = p[5 * (size_t)D4];
            float4 v6 = p[6 * (size_t)D4];
            float4 v7 = p[7 * (size_t)D4];
            acc.x = ((v0.x + v1.x) + (v2.x + v3.x)) + ((v4.x + v5.x) + (v6.x + v7.x));
            acc.y = ((v0.y + v1.y) + (v2.y + v3.y)) + ((v4.y + v5.y) + (v6.y + v7.y));
            acc.z = ((v0.z + v1.z) + (v2.z + v3.z)) + ((v4.z + v5.z) + (v6.z + v7.z));
            acc.w = ((v0.w + v1.w) + (v2.w + v3.w)) + ((v4.w + v5.w) + (v6.w + v7.w));
        } else {
            acc = make_float4(0.f, 0.f, 0.f, 0.f);
            for (int k = 0; k < n; ++k) {
                float4 v = p[(size_t)k * D4];
                acc.x += v.x; acc.y += v.y; acc.z += v.z; acc.w += v.w;
            }
        }
        o[d] = make_float4(acc.x * inv, acc.y * inv, acc.z * inv, acc.w * inv);
    }
}

extern "C" void kernel_launch(void* const* d_in, const int* in_sizes, int n_in,
                              void* d_out, int out_size, void* d_ws, size_t ws_size,
                              hipStream_t stream) {
    const float* x        = (const float*)d_in[0];   // (B, T, D) fp32
    const int*   lengths  = (const int*)d_in[1];     // (B,)
    const int*   spans    = (const int*)d_in[2];     // (B, S, 2)
    float*       out      = (float*)d_out;           // (B, S, D) fp32

    const int B  = in_sizes[1];
    const int S  = in_sizes[2] / (2 * B);
    const int D  = out_size / (B * S);
    const int T  = in_sizes[0] / (B * D);
    const int D4 = D / 4;                            // D=768 -> 192

    int block = ((D4 + 63) / 64) * 64;               // 192 for D=768
    if (block > 256) block = 256;
    if (block < 64)  block = 64;

    dim3 grid(B * S);
    span_mean_kernel<<<grid, dim3(block), 0, stream>>>(
        (const float4*)x, lengths, spans, (float4*)out, S, T, D4);
}